// Round 7
// baseline (10280.228 us; speedup 1.0000x reference)
//
#include <hip/hip_runtime.h>
#include <cstdint>
#include <cstddef>

#define B_  1024
#define T_  100
#define H_  256

typedef _Float16 f16x8 __attribute__((ext_vector_type(8)));
typedef float    f32x16 __attribute__((ext_vector_type(16)));

__device__ __forceinline__ float sigm(float x){ return 1.0f/(1.0f + __expf(-x)); }
__device__ __forceinline__ float tanh_(float x){ return 1.0f - 2.0f/(1.0f + __expf(2.0f*x)); }

// fp16 fragment-major weight pool offsets (elements).
// Frag layout per pool: fid = ((cc*4+g)*nkk + kk)*64 + lane, holding
// W[g*256 + cc*32 + (lane&31)][kk*16 + (lane>>5)*8 + 0..7]  (f16x8 per lane).
#define W_WHH1F 0
#define W_WHH1B 262144
#define W_WIH2F 524288
#define W_WIH2B 1048576
#define W_WHH2F 1572864
#define W_WHH2B 1835008
#define W_TOTAL 2097152

__global__ void pack_weights(const float* __restrict__ Whh1f, const float* __restrict__ Whh1b,
                             const float* __restrict__ Wih2f, const float* __restrict__ Wih2b,
                             const float* __restrict__ Whh2f, const float* __restrict__ Whh2b,
                             _Float16* __restrict__ dst)
{
  int fid = blockIdx.x*256 + threadIdx.x;   // 0 .. 262143 frags
  const float* src; int base, nkk, ksh, lf;
  if      (fid <  32768){ src=Whh1f; base=W_WHH1F; nkk=16; ksh=4; lf=fid; }
  else if (fid <  65536){ src=Whh1b; base=W_WHH1B; nkk=16; ksh=4; lf=fid-32768; }
  else if (fid < 131072){ src=Wih2f; base=W_WIH2F; nkk=32; ksh=5; lf=fid-65536; }
  else if (fid < 196608){ src=Wih2b; base=W_WIH2B; nkk=32; ksh=5; lf=fid-131072; }
  else if (fid < 229376){ src=Whh2f; base=W_WHH2F; nkk=16; ksh=4; lf=fid-196608; }
  else                  { src=Whh2b; base=W_WHH2B; nkk=16; ksh=4; lf=fid-229376; }
  int l  = lf & 63;
  int t  = lf >> 6;
  int kk = t & (nkk-1);
  int r  = t >> ksh;           // cc*4+g
  int g  = r & 3, cc = r >> 2;
  int K  = nkk*16;
  int n  = g*256 + cc*32 + (l & 31);
  int k  = kk*16 + ((l >> 5) << 3);
  const float4* s4 = (const float4*)(src + (size_t)n*K + k);
  float4 v0 = s4[0], v1 = s4[1];
  f16x8 o;
  o[0]=(_Float16)v0.x; o[1]=(_Float16)v0.y; o[2]=(_Float16)v0.z; o[3]=(_Float16)v0.w;
  o[4]=(_Float16)v1.x; o[5]=(_Float16)v1.y; o[6]=(_Float16)v1.z; o[7]=(_Float16)v1.w;
  *(f16x8*)(dst + (size_t)base + (size_t)lf*8) = o;
}

// ---------------- L1 persistent phase (block-local recurrence) ----------------
// 64 blocks x 512 threads (8 waves). Block (dir, rc) owns batch rows
// [rc*32, +32), computes ALL 256 h-cols each step -> recurrence is
// block-local; only __syncthreads needed. h in LDS (MFMA A-frag layout),
// c in registers. Weights streamed fragment-major from L2 each step with
// an explicit depth-4 register prefetch pipeline.
// bid map: dir = bid>>5 (round-5-validated: 97% weight L2 hit on this
// part's dispatch pattern; do NOT assume bid%8 XCD round-robin).
__global__ __launch_bounds__(512, 2)
void l1_phase(const _Float16* __restrict__ wpool,
              const float* __restrict__ Wih_f, const float* __restrict__ Wih_b,
              const float* __restrict__ bih_f, const float* __restrict__ bhh_f,
              const float* __restrict__ bih_b, const float* __restrict__ bhh_b,
              const float* __restrict__ xT, const float* __restrict__ mvec,
              const float* __restrict__ mask1, const float* __restrict__ mask2,
              _Float16* __restrict__ p1m)     // [T][B][512] fp16 (h*mask2)
{
  __shared__ __align__(16) _Float16 hlds[8192];   // 16KB: [kk][lane][8]
  const int bid = blockIdx.x;                     // 64 blocks
  const int dir = bid >> 5, rc = bid & 31;
  const int tid = threadIdx.x, lane = tid & 63, w = tid >> 6;
  const int b0 = rc*32;
  const int hcol = w*32 + (lane & 31);
  const _Float16* whhW = wpool + (dir ? W_WHH1B : W_WHH1F) + (size_t)(w*4)*16*512 + lane*8;

  #pragma unroll
  for (int i = 0; i < 16; i++) hlds[tid + 512*i] = (_Float16)0.f;

  const float* Wih = dir ? Wih_b : Wih_f;
  const float* bih = dir ? bih_b : bih_f;
  const float* bhh = dir ? bhh_b : bhh_f;
  float wi0[4], wi1[4], bs[4];
  #pragma unroll
  for (int g = 0; g < 4; g++){
    int n = g*256 + hcol;
    wi0[g] = Wih[n*2]; wi1[g] = Wih[n*2 + 1];
    bs[g]  = bih[n] + bhh[n];
  }
  int rowv[16]; float m1v[16], m2v[16], mvv[16], creg[16];
  #pragma unroll
  for (int r = 0; r < 16; r++){
    int row = (r & 3) + 8*(r >> 2) + 4*(lane >> 5);
    rowv[r] = row;
    int b = b0 + row;
    m1v[r] = mask1[(size_t)b*H_ + hcol];
    m2v[r] = mask2[(size_t)b*512 + dir*256 + hcol];
    mvv[r] = mvec[b];
    creg[r] = 0.0f;
  }
  const int wbase = (hcol >> 4)*512 + ((hcol >> 3) & 1)*256 + (hcol & 7);
  __syncthreads();

  for (int s = 0; s < T_; s++){
    const int tin = dir ? (T_-1-s) : s;
    f32x16 acc[4];
    #pragma unroll
    for (int g = 0; g < 4; g++)
      #pragma unroll
      for (int e = 0; e < 16; e++) acc[g][e] = 0.0f;

    // depth-4 register pipeline over 16 kk steps
    f16x8 bq[4][4], aq[4];
    #pragma unroll
    for (int p = 0; p < 4; p++){
      aq[p] = *(const f16x8*)(hlds + p*512 + lane*8);
      #pragma unroll
      for (int g = 0; g < 4; g++)
        bq[p][g] = *(const f16x8*)(whhW + (size_t)(g*16 + p)*512);
    }
    #pragma unroll
    for (int kk = 0; kk < 16; kk++){
      const int slot = kk & 3;
      f16x8 a  = aq[slot];
      f16x8 w0 = bq[slot][0], w1 = bq[slot][1], w2 = bq[slot][2], w3 = bq[slot][3];
      if (kk + 4 < 16){
        aq[slot] = *(const f16x8*)(hlds + (kk+4)*512 + lane*8);
        #pragma unroll
        for (int g = 0; g < 4; g++)
          bq[slot][g] = *(const f16x8*)(whhW + (size_t)(g*16 + kk + 4)*512);
      }
      acc[0] = __builtin_amdgcn_mfma_f32_32x32x16_f16(a, w0, acc[0], 0, 0, 0);
      acc[1] = __builtin_amdgcn_mfma_f32_32x32x16_f16(a, w1, acc[1], 0, 0, 0);
      acc[2] = __builtin_amdgcn_mfma_f32_32x32x16_f16(a, w2, acc[2], 0, 0, 0);
      acc[3] = __builtin_amdgcn_mfma_f32_32x32x16_f16(a, w3, acc[3], 0, 0, 0);
    }
    __syncthreads();     // all hlds reads done before overwrite

    #pragma unroll
    for (int r = 0; r < 16; r++){
      int b = b0 + rowv[r];
      float mv = mvv[r];
      float xd = xT[tin*B_ + b] - mv;
      float gi = acc[0][r] + xd*wi0[0] + mv*wi1[0] + bs[0];
      float gf = acc[1][r] + xd*wi0[1] + mv*wi1[1] + bs[1];
      float gg = acc[2][r] + xd*wi0[2] + mv*wi1[2] + bs[2];
      float go = acc[3][r] + xd*wi0[3] + mv*wi1[3] + bs[3];
      float ii = sigm(gi), ff = sigm(gf), g2 = tanh_(gg), oo = sigm(go);
      float cn = ff*creg[r] + ii*g2;
      creg[r] = cn;
      float h = oo*tanh_(cn);
      hlds[wbase + rowv[r]*8] = (_Float16)(h * m1v[r]);
      p1m[((size_t)s*B_ + b)*512 + dir*256 + hcol] = (_Float16)(h * m2v[r]);
    }
    __syncthreads();     // hlds fully written before next step's reads
  }
}

// ---------------- L2 persistent phase (block-local recurrence) ----------------
// Unified 48-step virtual K loop (16 Whh kk + 32 Wih kk), depth-4
// register prefetch for both A (global for Wih region) and B fragments.
__global__ __launch_bounds__(512, 2)
void l2_phase(const _Float16* __restrict__ wpool,
              const float* __restrict__ bih_f, const float* __restrict__ bhh_f,
              const float* __restrict__ bih_b, const float* __restrict__ bhh_b,
              const _Float16* __restrict__ p1m,
              const float* __restrict__ mask3, const float* __restrict__ mask4,
              const float* __restrict__ Wout,
              float* __restrict__ pred)
{
  __shared__ __align__(16) _Float16 hlds[8192];
  const int bid = blockIdx.x;
  const int dir = bid >> 5, rc = bid & 31;
  const int tid = threadIdx.x, lane = tid & 63, w = tid >> 6;
  const int b0 = rc*32;
  const int hcol = w*32 + (lane & 31);
  const _Float16* whhW = wpool + (dir ? W_WHH2B : W_WHH2F) + (size_t)(w*4)*16*512 + lane*8;
  const _Float16* wihW = wpool + (dir ? W_WIH2B : W_WIH2F) + (size_t)(w*4)*32*512 + lane*8;

  #pragma unroll
  for (int i = 0; i < 16; i++) hlds[tid + 512*i] = (_Float16)0.f;

  const float* bih = dir ? bih_b : bih_f;
  const float* bhh = dir ? bhh_b : bhh_f;
  float bs[4];
  #pragma unroll
  for (int g = 0; g < 4; g++) bs[g] = bih[g*256 + hcol] + bhh[g*256 + hcol];
  float wo = Wout[dir*256 + hcol];
  int rowv[16]; float m3v[16], m4v[16], creg[16];
  #pragma unroll
  for (int r = 0; r < 16; r++){
    int row = (r & 3) + 8*(r >> 2) + 4*(lane >> 5);
    rowv[r] = row;
    int b = b0 + row;
    m3v[r] = mask3[(size_t)b*H_ + hcol];
    m4v[r] = mask4[(size_t)b*512 + dir*256 + hcol] * wo;
    creg[r] = 0.0f;
  }
  const int wbase = (hcol >> 4)*512 + ((hcol >> 3) & 1)*256 + (hcol & 7);
  __syncthreads();

  for (int s = 0; s < T_; s++){
    const int tin = dir ? (T_-1-s) : s;
    const _Float16* arow2 = p1m + ((size_t)tin*B_ + b0 + (lane & 31))*512 + ((lane >> 5) << 3);

    f32x16 acc[4];
    #pragma unroll
    for (int g = 0; g < 4; g++)
      #pragma unroll
      for (int e = 0; e < 16; e++) acc[g][e] = 0.0f;

    // helpers (vs is compile-time constant under full unroll)
    #define A_FRAG(vs) ((vs) < 16 ? *(const f16x8*)(hlds + (vs)*512 + lane*8) \
                                  : *(const f16x8*)(arow2 + ((vs)-16)*16))
    #define B_FRAG(vs, g) ((vs) < 16 ? *(const f16x8*)(whhW + (size_t)((g)*16 + (vs))*512) \
                                     : *(const f16x8*)(wihW + (size_t)((g)*32 + ((vs)-16))*512))

    f16x8 bq[4][4], aq[4];
    #pragma unroll
    for (int p = 0; p < 4; p++){
      aq[p] = A_FRAG(p);
      #pragma unroll
      for (int g = 0; g < 4; g++) bq[p][g] = B_FRAG(p, g);
    }
    #pragma unroll
    for (int vs = 0; vs < 48; vs++){
      const int slot = vs & 3;
      f16x8 a  = aq[slot];
      f16x8 w0 = bq[slot][0], w1 = bq[slot][1], w2 = bq[slot][2], w3 = bq[slot][3];
      if (vs + 4 < 48){
        aq[slot] = A_FRAG(vs + 4);
        #pragma unroll
        for (int g = 0; g < 4; g++) bq[slot][g] = B_FRAG(vs + 4, g);
      }
      acc[0] = __builtin_amdgcn_mfma_f32_32x32x16_f16(a, w0, acc[0], 0, 0, 0);
      acc[1] = __builtin_amdgcn_mfma_f32_32x32x16_f16(a, w1, acc[1], 0, 0, 0);
      acc[2] = __builtin_amdgcn_mfma_f32_32x32x16_f16(a, w2, acc[2], 0, 0, 0);
      acc[3] = __builtin_amdgcn_mfma_f32_32x32x16_f16(a, w3, acc[3], 0, 0, 0);
    }
    #undef A_FRAG
    #undef B_FRAG
    __syncthreads();     // hlds reads done

    #pragma unroll
    for (int r = 0; r < 16; r++){
      int b = b0 + rowv[r];
      float gi = acc[0][r] + bs[0];
      float gf = acc[1][r] + bs[1];
      float gg = acc[2][r] + bs[2];
      float go = acc[3][r] + bs[3];
      float ii = sigm(gi), ff = sigm(gf), g2 = tanh_(gg), oo = sigm(go);
      float cn = ff*creg[r] + ii*g2;
      creg[r] = cn;
      float h = oo*tanh_(cn);
      hlds[wbase + rowv[r]*8] = (_Float16)(h * m3v[r]);
      float contrib = h * m4v[r];
      contrib += __shfl_xor(contrib, 16);
      contrib += __shfl_xor(contrib, 8);
      contrib += __shfl_xor(contrib, 4);
      contrib += __shfl_xor(contrib, 2);
      contrib += __shfl_xor(contrib, 1);
      if ((lane & 31) == 0) atomicAdd(&pred[(size_t)b*T_ + s], contrib);
    }
    __syncthreads();
  }
}

__global__ void prep_kernel(const float* __restrict__ x0, float* __restrict__ mvec)
{
  int b = blockIdx.x*blockDim.x + threadIdx.x;
  if (b < B_){
    float ssum = 0.0f;
    for (int t = 0; t < T_; t++) ssum += x0[b*T_ + t];
    mvec[b] = ssum * (1.0f / T_);
  }
}

// xT[t*B + b] = x0[b*T + t]  (coalesced write, small)
__global__ void prep2_kernel(const float* __restrict__ x0, float* __restrict__ xT)
{
  int idx = blockIdx.x*256 + threadIdx.x;
  if (idx < B_*T_){
    int t = idx >> 10;           // B_ = 1024
    int b = idx & 1023;
    xT[idx] = x0[b*T_ + t];
  }
}

__global__ void final_kernel(const float* __restrict__ pred,
                             const float* __restrict__ mvec,
                             const float* __restrict__ bout,
                             float* __restrict__ out)
{
  int idx = blockIdx.x*256 + threadIdx.x;
  if (idx < B_*T_){
    int b = idx / T_;
    out[idx] = pred[idx] + bout[0] + mvec[b];
  }
}

extern "C" void kernel_launch(void* const* d_in, const int* in_sizes, int n_in,
                              void* d_out, int out_size, void* d_ws, size_t ws_size,
                              hipStream_t stream)
{
  (void)in_sizes; (void)n_in; (void)out_size; (void)ws_size;
  const float* x0    = (const float*)d_in[0];
  const float* Wih1f = (const float*)d_in[1];
  const float* Whh1f = (const float*)d_in[2];
  const float* bih1f = (const float*)d_in[3];
  const float* bhh1f = (const float*)d_in[4];
  const float* Wih1b = (const float*)d_in[5];
  const float* Whh1b = (const float*)d_in[6];
  const float* bih1b = (const float*)d_in[7];
  const float* bhh1b = (const float*)d_in[8];
  const float* Wih2f = (const float*)d_in[9];
  const float* Whh2f = (const float*)d_in[10];
  const float* bih2f = (const float*)d_in[11];
  const float* bhh2f = (const float*)d_in[12];
  const float* Wih2b = (const float*)d_in[13];
  const float* Whh2b = (const float*)d_in[14];
  const float* bih2b = (const float*)d_in[15];
  const float* bhh2b = (const float*)d_in[16];
  const float* Wout  = (const float*)d_in[17];
  const float* bout  = (const float*)d_in[18];
  const float* mask1 = (const float*)d_in[19];
  const float* mask2 = (const float*)d_in[20];
  const float* mask3 = (const float*)d_in[21];
  const float* mask4 = (const float*)d_in[22];
  float* out = (float*)d_out;

  // Workspace layout (~110 MB)
  char* ws = (char*)d_ws;
  size_t off = 0;
  _Float16* wpool = (_Float16*)(ws + off); off += (size_t)W_TOTAL*2;        // 4.2 MB
  _Float16* p1m   = (_Float16*)(ws + off); off += (size_t)T_*B_*512*2;      // 104.8 MB
  float* pred = (float*)(ws + off); off += (size_t)B_*T_*4;                 // 0.4 MB
  float* xT   = (float*)(ws + off); off += (size_t)B_*T_*4;                 // 0.4 MB
  float* mvec = (float*)(ws + off); off += 4096;

  hipMemsetAsync(pred, 0, (size_t)B_*T_*4, stream);

  pack_weights<<<dim3(1024), dim3(256), 0, stream>>>(
      Whh1f, Whh1b, Wih2f, Wih2b, Whh2f, Whh2b, wpool);
  prep_kernel<<<dim3(4), dim3(256), 0, stream>>>(x0, mvec);
  prep2_kernel<<<dim3((B_*T_ + 255)/256), dim3(256), 0, stream>>>(x0, xT);

  l1_phase<<<dim3(64), dim3(512), 0, stream>>>(wpool, Wih1f, Wih1b,
      bih1f, bhh1f, bih1b, bhh1b, xT, mvec, mask1, mask2, p1m);
  l2_phase<<<dim3(64), dim3(512), 0, stream>>>(wpool, bih2f, bhh2f,
      bih2b, bhh2b, p1m, mask3, mask4, Wout, pred);
  final_kernel<<<dim3((B_*T_ + 255)/256), dim3(256), 0, stream>>>(pred, mvec, bout, out);
}

// Round 8
// 10138.856 us; speedup vs baseline: 1.0139x; 1.0139x over previous
//
#include <hip/hip_runtime.h>
#include <cstdint>
#include <cstddef>

#define B_  1024
#define T_  100
#define H_  256

typedef _Float16 f16x8 __attribute__((ext_vector_type(8)));
typedef float    f32x16 __attribute__((ext_vector_type(16)));

__device__ __forceinline__ float sigm(float x){ return 1.0f/(1.0f + __expf(-x)); }
__device__ __forceinline__ float tanh_(float x){ return 1.0f - 2.0f/(1.0f + __expf(2.0f*x)); }

// fp16 fragment-major weight pool offsets (elements).
// Frag layout per pool: fid = ((cc*4+g)*nkk + kk)*64 + lane, holding
// W[g*256 + cc*32 + (lane&31)][kk*16 + (lane>>5)*8 + 0..7]  (f16x8 per lane).
#define W_WHH1F 0
#define W_WHH1B 262144
#define W_WIH2F 524288
#define W_WIH2B 1048576
#define W_WHH2F 1572864
#define W_WHH2B 1835008
#define W_TOTAL 2097152

__global__ void pack_weights(const float* __restrict__ Whh1f, const float* __restrict__ Whh1b,
                             const float* __restrict__ Wih2f, const float* __restrict__ Wih2b,
                             const float* __restrict__ Whh2f, const float* __restrict__ Whh2b,
                             _Float16* __restrict__ dst)
{
  int fid = blockIdx.x*256 + threadIdx.x;   // 0 .. 262143 frags
  const float* src; int base, nkk, ksh, lf;
  if      (fid <  32768){ src=Whh1f; base=W_WHH1F; nkk=16; ksh=4; lf=fid; }
  else if (fid <  65536){ src=Whh1b; base=W_WHH1B; nkk=16; ksh=4; lf=fid-32768; }
  else if (fid < 131072){ src=Wih2f; base=W_WIH2F; nkk=32; ksh=5; lf=fid-65536; }
  else if (fid < 196608){ src=Wih2b; base=W_WIH2B; nkk=32; ksh=5; lf=fid-131072; }
  else if (fid < 229376){ src=Whh2f; base=W_WHH2F; nkk=16; ksh=4; lf=fid-196608; }
  else                  { src=Whh2b; base=W_WHH2B; nkk=16; ksh=4; lf=fid-229376; }
  int l  = lf & 63;
  int t  = lf >> 6;
  int kk = t & (nkk-1);
  int r  = t >> ksh;           // cc*4+g
  int g  = r & 3, cc = r >> 2;
  int K  = nkk*16;
  int n  = g*256 + cc*32 + (l & 31);
  int k  = kk*16 + ((l >> 5) << 3);
  const float4* s4 = (const float4*)(src + (size_t)n*K + k);
  float4 v0 = s4[0], v1 = s4[1];
  f16x8 o;
  o[0]=(_Float16)v0.x; o[1]=(_Float16)v0.y; o[2]=(_Float16)v0.z; o[3]=(_Float16)v0.w;
  o[4]=(_Float16)v1.x; o[5]=(_Float16)v1.y; o[6]=(_Float16)v1.z; o[7]=(_Float16)v1.w;
  *(f16x8*)(dst + (size_t)base + (size_t)lf*8) = o;
}

// ---------------- L1 persistent phase (block-local recurrence) ----------------
// 64 blocks x 512 threads (8 waves). Block (dir, rc) owns batch rows
// [rc*32, +32), computes ALL 256 h-cols each step -> recurrence is
// block-local; only __syncthreads needed. h in LDS (MFMA A-frag layout),
// c in registers. Weights streamed fragment-major from L2 each step with
// a depth-4 register prefetch pipeline.
// waves_per_eu(2,2): pins exactly 2 waves/SIMD (the only occupancy this
// 64-block launch can have anyway) -> allocator may use 256 VGPRs, which
// the pipeline needs. Rounds 6/7 spilled at the 128-VGPR default: FETCH
// exploded 255MB -> 4.7GB from scratch reloads.
__global__ __launch_bounds__(512)
__attribute__((amdgpu_waves_per_eu(2, 2)))
void l1_phase(const _Float16* __restrict__ wpool,
              const float* __restrict__ Wih_f, const float* __restrict__ Wih_b,
              const float* __restrict__ bih_f, const float* __restrict__ bhh_f,
              const float* __restrict__ bih_b, const float* __restrict__ bhh_b,
              const float* __restrict__ xT, const float* __restrict__ mvec,
              const float* __restrict__ mask1, const float* __restrict__ mask2,
              _Float16* __restrict__ p1m)     // [T][B][512] fp16 (h*mask2)
{
  __shared__ __align__(16) _Float16 hlds[8192];   // 16KB: [kk][lane][8]
  const int bid = blockIdx.x;                     // 64 blocks
  const int dir = bid >> 5, rc = bid & 31;        // round-5-validated map
  const int tid = threadIdx.x, lane = tid & 63, w = tid >> 6;
  const int b0 = rc*32;
  const int hi4 = (lane >> 5) << 2;               // 4*(lane>>5)
  const int hcol = w*32 + (lane & 31);
  const _Float16* whhW = wpool + (dir ? W_WHH1B : W_WHH1F) + (size_t)(w*4)*16*512 + lane*8;

  #pragma unroll
  for (int i = 0; i < 16; i++) hlds[tid + 512*i] = (_Float16)0.f;

  const float* Wih = dir ? Wih_b : Wih_f;
  const float* bih = dir ? bih_b : bih_f;
  const float* bhh = dir ? bhh_b : bhh_f;
  float wi0[4], wi1[4], bs[4];
  #pragma unroll
  for (int g = 0; g < 4; g++){
    int n = g*256 + hcol;
    wi0[g] = Wih[n*2]; wi1[g] = Wih[n*2 + 1];
    bs[g]  = bih[n] + bhh[n];
  }
  float m1v[16], m2v[16], mvv[16], creg[16];
  #pragma unroll
  for (int r = 0; r < 16; r++){
    int b = b0 + (r & 3) + 8*(r >> 2) + hi4;
    m1v[r] = mask1[(size_t)b*H_ + hcol];
    m2v[r] = mask2[(size_t)b*512 + dir*256 + hcol];
    mvv[r] = mvec[b];
    creg[r] = 0.0f;
  }
  const int wbase = (hcol >> 4)*512 + ((hcol >> 3) & 1)*256 + (hcol & 7);
  __syncthreads();

  for (int s = 0; s < T_; s++){
    const int tin = dir ? (T_-1-s) : s;
    f32x16 acc[4];
    #pragma unroll
    for (int g = 0; g < 4; g++)
      #pragma unroll
      for (int e = 0; e < 16; e++) acc[g][e] = 0.0f;

    // depth-4 register pipeline over 16 kk steps
    f16x8 bq[4][4], aq[4];
    #pragma unroll
    for (int p = 0; p < 4; p++){
      aq[p] = *(const f16x8*)(hlds + p*512 + lane*8);
      #pragma unroll
      for (int g = 0; g < 4; g++)
        bq[p][g] = *(const f16x8*)(whhW + (size_t)(g*16 + p)*512);
    }
    #pragma unroll
    for (int kk = 0; kk < 16; kk++){
      const int slot = kk & 3;
      f16x8 a  = aq[slot];
      f16x8 w0 = bq[slot][0], w1 = bq[slot][1], w2 = bq[slot][2], w3 = bq[slot][3];
      if (kk + 4 < 16){
        aq[slot] = *(const f16x8*)(hlds + (kk+4)*512 + lane*8);
        #pragma unroll
        for (int g = 0; g < 4; g++)
          bq[slot][g] = *(const f16x8*)(whhW + (size_t)(g*16 + kk + 4)*512);
      }
      acc[0] = __builtin_amdgcn_mfma_f32_32x32x16_f16(a, w0, acc[0], 0, 0, 0);
      acc[1] = __builtin_amdgcn_mfma_f32_32x32x16_f16(a, w1, acc[1], 0, 0, 0);
      acc[2] = __builtin_amdgcn_mfma_f32_32x32x16_f16(a, w2, acc[2], 0, 0, 0);
      acc[3] = __builtin_amdgcn_mfma_f32_32x32x16_f16(a, w3, acc[3], 0, 0, 0);
    }
    __syncthreads();     // all hlds reads done before overwrite

    #pragma unroll
    for (int r = 0; r < 16; r++){
      const int row = (r & 3) + 8*(r >> 2) + hi4;
      const int b = b0 + row;
      float mv = mvv[r];
      float xd = xT[tin*B_ + b] - mv;
      float gi = acc[0][r] + xd*wi0[0] + mv*wi1[0] + bs[0];
      float gf = acc[1][r] + xd*wi0[1] + mv*wi1[1] + bs[1];
      float gg = acc[2][r] + xd*wi0[2] + mv*wi1[2] + bs[2];
      float go = acc[3][r] + xd*wi0[3] + mv*wi1[3] + bs[3];
      float ii = sigm(gi), ff = sigm(gf), g2 = tanh_(gg), oo = sigm(go);
      float cn = ff*creg[r] + ii*g2;
      creg[r] = cn;
      float h = oo*tanh_(cn);
      hlds[wbase + row*8] = (_Float16)(h * m1v[r]);
      p1m[((size_t)s*B_ + b)*512 + dir*256 + hcol] = (_Float16)(h * m2v[r]);
    }
    __syncthreads();     // hlds fully written before next step's reads
  }
}

// ---------------- L2 persistent phase (block-local recurrence) ----------------
// Unified 48-step virtual K loop (16 Whh kk + 32 Wih kk), depth-4
// register prefetch for both A (global for Wih region) and B fragments.
__global__ __launch_bounds__(512)
__attribute__((amdgpu_waves_per_eu(2, 2)))
void l2_phase(const _Float16* __restrict__ wpool,
              const float* __restrict__ bih_f, const float* __restrict__ bhh_f,
              const float* __restrict__ bih_b, const float* __restrict__ bhh_b,
              const _Float16* __restrict__ p1m,
              const float* __restrict__ mask3, const float* __restrict__ mask4,
              const float* __restrict__ Wout,
              float* __restrict__ pred)
{
  __shared__ __align__(16) _Float16 hlds[8192];
  const int bid = blockIdx.x;
  const int dir = bid >> 5, rc = bid & 31;
  const int tid = threadIdx.x, lane = tid & 63, w = tid >> 6;
  const int b0 = rc*32;
  const int hi4 = (lane >> 5) << 2;
  const int hcol = w*32 + (lane & 31);
  const _Float16* whhW = wpool + (dir ? W_WHH2B : W_WHH2F) + (size_t)(w*4)*16*512 + lane*8;
  const _Float16* wihW = wpool + (dir ? W_WIH2B : W_WIH2F) + (size_t)(w*4)*32*512 + lane*8;

  #pragma unroll
  for (int i = 0; i < 16; i++) hlds[tid + 512*i] = (_Float16)0.f;

  const float* bih = dir ? bih_b : bih_f;
  const float* bhh = dir ? bhh_b : bhh_f;
  float bs[4];
  #pragma unroll
  for (int g = 0; g < 4; g++) bs[g] = bih[g*256 + hcol] + bhh[g*256 + hcol];
  float wo = Wout[dir*256 + hcol];
  float m3v[16], m4v[16], creg[16];
  #pragma unroll
  for (int r = 0; r < 16; r++){
    int b = b0 + (r & 3) + 8*(r >> 2) + hi4;
    m3v[r] = mask3[(size_t)b*H_ + hcol];
    m4v[r] = mask4[(size_t)b*512 + dir*256 + hcol] * wo;
    creg[r] = 0.0f;
  }
  const int wbase = (hcol >> 4)*512 + ((hcol >> 3) & 1)*256 + (hcol & 7);
  __syncthreads();

  for (int s = 0; s < T_; s++){
    const int tin = dir ? (T_-1-s) : s;
    const _Float16* arow2 = p1m + ((size_t)tin*B_ + b0 + (lane & 31))*512 + ((lane >> 5) << 3);

    f32x16 acc[4];
    #pragma unroll
    for (int g = 0; g < 4; g++)
      #pragma unroll
      for (int e = 0; e < 16; e++) acc[g][e] = 0.0f;

    // helpers (vs is compile-time constant under full unroll)
    #define A_FRAG(vs) ((vs) < 16 ? *(const f16x8*)(hlds + (vs)*512 + lane*8) \
                                  : *(const f16x8*)(arow2 + ((vs)-16)*16))
    #define B_FRAG(vs, g) ((vs) < 16 ? *(const f16x8*)(whhW + (size_t)((g)*16 + (vs))*512) \
                                     : *(const f16x8*)(wihW + (size_t)((g)*32 + ((vs)-16))*512))

    f16x8 bq[4][4], aq[4];
    #pragma unroll
    for (int p = 0; p < 4; p++){
      aq[p] = A_FRAG(p);
      #pragma unroll
      for (int g = 0; g < 4; g++) bq[p][g] = B_FRAG(p, g);
    }
    #pragma unroll
    for (int vs = 0; vs < 48; vs++){
      const int slot = vs & 3;
      f16x8 a  = aq[slot];
      f16x8 w0 = bq[slot][0], w1 = bq[slot][1], w2 = bq[slot][2], w3 = bq[slot][3];
      if (vs + 4 < 48){
        aq[slot] = A_FRAG(vs + 4);
        #pragma unroll
        for (int g = 0; g < 4; g++) bq[slot][g] = B_FRAG(vs + 4, g);
      }
      acc[0] = __builtin_amdgcn_mfma_f32_32x32x16_f16(a, w0, acc[0], 0, 0, 0);
      acc[1] = __builtin_amdgcn_mfma_f32_32x32x16_f16(a, w1, acc[1], 0, 0, 0);
      acc[2] = __builtin_amdgcn_mfma_f32_32x32x16_f16(a, w2, acc[2], 0, 0, 0);
      acc[3] = __builtin_amdgcn_mfma_f32_32x32x16_f16(a, w3, acc[3], 0, 0, 0);
    }
    #undef A_FRAG
    #undef B_FRAG
    __syncthreads();     // hlds reads done

    #pragma unroll
    for (int r = 0; r < 16; r++){
      const int row = (r & 3) + 8*(r >> 2) + hi4;
      const int b = b0 + row;
      float gi = acc[0][r] + bs[0];
      float gf = acc[1][r] + bs[1];
      float gg = acc[2][r] + bs[2];
      float go = acc[3][r] + bs[3];
      float ii = sigm(gi), ff = sigm(gf), g2 = tanh_(gg), oo = sigm(go);
      float cn = ff*creg[r] + ii*g2;
      creg[r] = cn;
      float h = oo*tanh_(cn);
      hlds[wbase + row*8] = (_Float16)(h * m3v[r]);
      float contrib = h * m4v[r];
      contrib += __shfl_xor(contrib, 16);
      contrib += __shfl_xor(contrib, 8);
      contrib += __shfl_xor(contrib, 4);
      contrib += __shfl_xor(contrib, 2);
      contrib += __shfl_xor(contrib, 1);
      if ((lane & 31) == 0) atomicAdd(&pred[(size_t)b*T_ + s], contrib);
    }
    __syncthreads();
  }
}

__global__ void prep_kernel(const float* __restrict__ x0, float* __restrict__ mvec)
{
  int b = blockIdx.x*blockDim.x + threadIdx.x;
  if (b < B_){
    float ssum = 0.0f;
    for (int t = 0; t < T_; t++) ssum += x0[b*T_ + t];
    mvec[b] = ssum * (1.0f / T_);
  }
}

// xT[t*B + b] = x0[b*T + t]  (coalesced write, small)
__global__ void prep2_kernel(const float* __restrict__ x0, float* __restrict__ xT)
{
  int idx = blockIdx.x*256 + threadIdx.x;
  if (idx < B_*T_){
    int t = idx >> 10;           // B_ = 1024
    int b = idx & 1023;
    xT[idx] = x0[b*T_ + t];
  }
}

__global__ void final_kernel(const float* __restrict__ pred,
                             const float* __restrict__ mvec,
                             const float* __restrict__ bout,
                             float* __restrict__ out)
{
  int idx = blockIdx.x*256 + threadIdx.x;
  if (idx < B_*T_){
    int b = idx / T_;
    out[idx] = pred[idx] + bout[0] + mvec[b];
  }
}

extern "C" void kernel_launch(void* const* d_in, const int* in_sizes, int n_in,
                              void* d_out, int out_size, void* d_ws, size_t ws_size,
                              hipStream_t stream)
{
  (void)in_sizes; (void)n_in; (void)out_size; (void)ws_size;
  const float* x0    = (const float*)d_in[0];
  const float* Wih1f = (const float*)d_in[1];
  const float* Whh1f = (const float*)d_in[2];
  const float* bih1f = (const float*)d_in[3];
  const float* bhh1f = (const float*)d_in[4];
  const float* Wih1b = (const float*)d_in[5];
  const float* Whh1b = (const float*)d_in[6];
  const float* bih1b = (const float*)d_in[7];
  const float* bhh1b = (const float*)d_in[8];
  const float* Wih2f = (const float*)d_in[9];
  const float* Whh2f = (const float*)d_in[10];
  const float* bih2f = (const float*)d_in[11];
  const float* bhh2f = (const float*)d_in[12];
  const float* Wih2b = (const float*)d_in[13];
  const float* Whh2b = (const float*)d_in[14];
  const float* bih2b = (const float*)d_in[15];
  const float* bhh2b = (const float*)d_in[16];
  const float* Wout  = (const float*)d_in[17];
  const float* bout  = (const float*)d_in[18];
  const float* mask1 = (const float*)d_in[19];
  const float* mask2 = (const float*)d_in[20];
  const float* mask3 = (const float*)d_in[21];
  const float* mask4 = (const float*)d_in[22];
  float* out = (float*)d_out;

  // Workspace layout (~110 MB)
  char* ws = (char*)d_ws;
  size_t off = 0;
  _Float16* wpool = (_Float16*)(ws + off); off += (size_t)W_TOTAL*2;        // 4.2 MB
  _Float16* p1m   = (_Float16*)(ws + off); off += (size_t)T_*B_*512*2;      // 104.8 MB
  float* pred = (float*)(ws + off); off += (size_t)B_*T_*4;                 // 0.4 MB
  float* xT   = (float*)(ws + off); off += (size_t)B_*T_*4;                 // 0.4 MB
  float* mvec = (float*)(ws + off); off += 4096;

  hipMemsetAsync(pred, 0, (size_t)B_*T_*4, stream);

  pack_weights<<<dim3(1024), dim3(256), 0, stream>>>(
      Whh1f, Whh1b, Wih2f, Wih2b, Whh2f, Whh2b, wpool);
  prep_kernel<<<dim3(4), dim3(256), 0, stream>>>(x0, mvec);
  prep2_kernel<<<dim3((B_*T_ + 255)/256), dim3(256), 0, stream>>>(x0, xT);

  l1_phase<<<dim3(64), dim3(512), 0, stream>>>(wpool, Wih1f, Wih1b,
      bih1f, bhh1f, bih1b, bhh1b, xT, mvec, mask1, mask2, p1m);
  l2_phase<<<dim3(64), dim3(512), 0, stream>>>(wpool, bih2f, bhh2f,
      bih2b, bhh2b, p1m, mask3, mask4, Wout, pred);
  final_kernel<<<dim3((B_*T_ + 255)/256), dim3(256), 0, stream>>>(pred, mvec, bout, out);
}

// Round 9
// 6055.754 us; speedup vs baseline: 1.6976x; 1.6743x over previous
//
#include <hip/hip_runtime.h>
#include <cstdint>
#include <cstddef>

#define B_  1024
#define T_  100
#define H_  256

typedef _Float16 f16x8 __attribute__((ext_vector_type(8)));
typedef float    f32x16 __attribute__((ext_vector_type(16)));

__device__ __forceinline__ float sigm(float x){ return 1.0f/(1.0f + __expf(-x)); }
__device__ __forceinline__ float tanh_(float x){ return 1.0f - 2.0f/(1.0f + __expf(2.0f*x)); }

// Async global->LDS DMA: 16B per lane, LDS dest = base + lane*16 (HW rule).
// AS casts via integers: flat==global numerically (AS1); LDS aperture is
// 4GiB-aligned so low 32 bits of a flat LDS pointer are the LDS offset (AS3).
__device__ __forceinline__ void gll16(const _Float16* g, const _Float16* l){
  __builtin_amdgcn_global_load_lds(
      (const __attribute__((address_space(1))) void*)(uintptr_t)g,
      (__attribute__((address_space(3))) void*)(uint32_t)(uintptr_t)l,
      16, 0, 0);
}
#define WAITV(N) do{ asm volatile("s_waitcnt vmcnt(" #N ")" ::: "memory"); \
                     __builtin_amdgcn_sched_barrier(0); }while(0)
#define WAITL0   do{ asm volatile("s_waitcnt lgkmcnt(0)" ::: "memory"); }while(0)

// fp16 weight pool: per-(dir,wave) contiguous fragment STREAMS in exact
// consumption order. One fragment = 1KB = 64 lanes x 16B; lane l holds
// W[n(l&31)][k(l>>5)] per MFMA B layout.
// L1 stream (per dir,w): 64 frags  = vs(0..15: Whh1 kk) x g(0..3)
// L2 stream (per dir,w): 192 frags = vs(0..31: Wih2 kk; 32..47: Whh2 kk) x g
#define W_L1S 0
#define W_L2S 524288
#define W_TOTAL 2097152

__global__ void pack_weights(const float* __restrict__ Whh1f, const float* __restrict__ Whh1b,
                             const float* __restrict__ Wih2f, const float* __restrict__ Wih2b,
                             const float* __restrict__ Whh2f, const float* __restrict__ Whh2b,
                             _Float16* __restrict__ dst)
{
  int u = blockIdx.x*256 + threadIdx.x;       // 0..262143 (16B units)
  int lane = u & 63;
  int frag = u >> 6;                          // 0..4095
  const float* src; int n, k, K;
  if (frag < 1024){                           // L1 streams
    int dir = frag >> 9, rem = frag & 511;
    int w = rem >> 6, f = rem & 63;
    int vs = f >> 2, g = f & 3;
    src = dir ? Whh1b : Whh1f; K = 256;
    n = g*256 + w*32 + (lane & 31);
    k = vs*16 + ((lane >> 5) << 3);
  } else {                                    // L2 streams
    int fr = frag - 1024;
    int dir = fr >= 1536;
    int r2 = dir ? fr - 1536 : fr;
    int w = r2 / 192, f = r2 % 192;
    int vs = f >> 2, g = f & 3;
    n = g*256 + w*32 + (lane & 31);
    if (vs < 32){ src = dir ? Wih2b : Wih2f; K = 512; k = vs*16 + ((lane >> 5) << 3); }
    else        { src = dir ? Whh2b : Whh2f; K = 256; k = (vs-32)*16 + ((lane >> 5) << 3); }
  }
  const float4* s4 = (const float4*)(src + (size_t)n*K + k);
  float4 v0 = s4[0], v1 = s4[1];
  f16x8 o;
  o[0]=(_Float16)v0.x; o[1]=(_Float16)v0.y; o[2]=(_Float16)v0.z; o[3]=(_Float16)v0.w;
  o[4]=(_Float16)v1.x; o[5]=(_Float16)v1.y; o[6]=(_Float16)v1.z; o[7]=(_Float16)v1.w;
  *(f16x8*)(dst + (size_t)frag*512 + lane*8) = o;
}

// ---------------- L1 persistent phase ----------------
// 64 blocks x 512 threads (8 waves). Block (dir=bid>>5, rc) owns rows
// [rc*32,+32), all 256 h-cols -> recurrence block-local. h in LDS
// (smem[0..8192), MFMA A-frag layout). Weight fragments DMA'd per-wave
// through a private 2-slot x 4KB LDS ring with counted vmcnt (never 0
// mid-loop). No barriers in the K-loop; 2 syncthreads/step for h.
__global__ __launch_bounds__(512)
void l1_phase(const _Float16* __restrict__ wpool,
              const float* __restrict__ Wih_f, const float* __restrict__ Wih_b,
              const float* __restrict__ bih_f, const float* __restrict__ bhh_f,
              const float* __restrict__ bih_b, const float* __restrict__ bhh_b,
              const float* __restrict__ xT, const float* __restrict__ mvec,
              const float* __restrict__ mask1, const float* __restrict__ mask2,
              _Float16* __restrict__ p1m)     // [T][B][512] fp16 (h*mask2)
{
  __shared__ __align__(16) _Float16 smem[8192 + 8*4096];   // 16KB h + 64KB rings
  const int bid = blockIdx.x;
  const int dir = bid >> 5, rc = bid & 31;
  const int tid = threadIdx.x, lane = tid & 63, w = tid >> 6;
  const int b0 = rc*32;
  const int hi4 = (lane >> 5) << 2;
  const int hcol = w*32 + (lane & 31);
  const _Float16* wsw = wpool + W_L1S + (size_t)(dir*8 + w)*64*512 + lane*8;
  _Float16* ringw = smem + 8192 + w*4096;

  #pragma unroll
  for (int i = 0; i < 16; i++) smem[tid + 512*i] = (_Float16)0.f;

  const float* Wih = dir ? Wih_b : Wih_f;
  const float* bih = dir ? bih_b : bih_f;
  const float* bhh = dir ? bhh_b : bhh_f;
  float wi0[4], wi1[4], bs[4];
  #pragma unroll
  for (int g = 0; g < 4; g++){
    int n = g*256 + hcol;
    wi0[g] = Wih[n*2]; wi1[g] = Wih[n*2 + 1];
    bs[g]  = bih[n] + bhh[n];
  }
  float m1v[16], m2v[16], creg[16];
  #pragma unroll
  for (int r = 0; r < 16; r++){
    int b = b0 + (r & 3) + 8*(r >> 2) + hi4;
    m1v[r] = mask1[(size_t)b*H_ + hcol];
    m2v[r] = mask2[(size_t)b*512 + dir*256 + hcol];
    creg[r] = 0.0f;
  }
  const int wbase = (hcol >> 4)*512 + ((hcol >> 3) & 1)*256 + (hcol & 7);
  __syncthreads();

#define L1_ISSUE(c, slot) do{ \
    const _Float16* gp_ = wsw + (size_t)(c)*2048; \
    _Float16* lp_ = ringw + (slot)*2048; \
    gll16(gp_,        lp_); \
    gll16(gp_ +  512, lp_ +  512); \
    gll16(gp_ + 1024, lp_ + 1024); \
    gll16(gp_ + 1536, lp_ + 1536); }while(0)
#define L1_CONSUME(c, slot) do{ \
    f16x8 a_ = *(const f16x8*)(smem + (c)*512 + lane*8); \
    const _Float16* rb_ = ringw + (slot)*2048 + lane*8; \
    f16x8 b0_ = *(const f16x8*)(rb_); \
    f16x8 b1_ = *(const f16x8*)(rb_ +  512); \
    f16x8 b2_ = *(const f16x8*)(rb_ + 1024); \
    f16x8 b3_ = *(const f16x8*)(rb_ + 1536); \
    acc[0] = __builtin_amdgcn_mfma_f32_32x32x16_f16(a_, b0_, acc[0], 0,0,0); \
    acc[1] = __builtin_amdgcn_mfma_f32_32x32x16_f16(a_, b1_, acc[1], 0,0,0); \
    acc[2] = __builtin_amdgcn_mfma_f32_32x32x16_f16(a_, b2_, acc[2], 0,0,0); \
    acc[3] = __builtin_amdgcn_mfma_f32_32x32x16_f16(a_, b3_, acc[3], 0,0,0); }while(0)

  for (int s = 0; s < T_; s++){
    const int tin = dir ? (T_-1-s) : s;
    f32x16 acc[4];
    #pragma unroll
    for (int g = 0; g < 4; g++)
      #pragma unroll
      for (int e = 0; e < 16; e++) acc[g][e] = 0.0f;

    L1_ISSUE(0,0); L1_ISSUE(1,1);
    for (int c = 0; c < 14; c += 2){
      WAITV(4); L1_CONSUME(c,0);   WAITL0; L1_ISSUE(c+2,0);
      WAITV(4); L1_CONSUME(c+1,1); WAITL0; L1_ISSUE(c+3,1);
    }
    WAITV(4); L1_CONSUME(14,0);
    WAITV(0); L1_CONSUME(15,1);

    __syncthreads();     // all smem-h reads done before overwrite

    #pragma unroll
    for (int r = 0; r < 16; r++){
      const int row = (r & 3) + 8*(r >> 2) + hi4;
      const int b = b0 + row;
      float mv = mvec[b];
      float xd = xT[tin*B_ + b] - mv;
      float gi = acc[0][r] + xd*wi0[0] + mv*wi1[0] + bs[0];
      float gf = acc[1][r] + xd*wi0[1] + mv*wi1[1] + bs[1];
      float gg = acc[2][r] + xd*wi0[2] + mv*wi1[2] + bs[2];
      float go = acc[3][r] + xd*wi0[3] + mv*wi1[3] + bs[3];
      float ii = sigm(gi), ff = sigm(gf), g2 = tanh_(gg), oo = sigm(go);
      float cn = ff*creg[r] + ii*g2;
      creg[r] = cn;
      float h = oo*tanh_(cn);
      smem[wbase + row*8] = (_Float16)(h * m1v[r]);
      p1m[((size_t)s*B_ + b)*512 + dir*256 + hcol] = (_Float16)(h * m2v[r]);
    }
    __syncthreads();     // h fully written before next step's reads
  }
#undef L1_ISSUE
#undef L1_CONSUME
}

// ---------------- L2 persistent phase ----------------
// 48-step virtual K: vs 0..31 input GEMM (A from p1m via counted plain
// loads, double-buffered regs), vs 32..47 recurrent (A from smem-h).
// B fragments DMA'd through per-wave 2-slot rings, counted vmcnt.
__global__ __launch_bounds__(512)
void l2_phase(const _Float16* __restrict__ wpool,
              const float* __restrict__ bih_f, const float* __restrict__ bhh_f,
              const float* __restrict__ bih_b, const float* __restrict__ bhh_b,
              const _Float16* __restrict__ p1m,
              const float* __restrict__ mask3, const float* __restrict__ mask4,
              const float* __restrict__ Wout,
              float* __restrict__ pred)
{
  __shared__ __align__(16) _Float16 smem[8192 + 8*4096];
  const int bid = blockIdx.x;
  const int dir = bid >> 5, rc = bid & 31;
  const int tid = threadIdx.x, lane = tid & 63, w = tid >> 6;
  const int b0 = rc*32;
  const int hi4 = (lane >> 5) << 2;
  const int hcol = w*32 + (lane & 31);
  const _Float16* wsw2 = wpool + W_L2S + (size_t)(dir*8 + w)*192*512 + lane*8;
  _Float16* ringw = smem + 8192 + w*4096;

  #pragma unroll
  for (int i = 0; i < 16; i++) smem[tid + 512*i] = (_Float16)0.f;

  const float* bih = dir ? bih_b : bih_f;
  const float* bhh = dir ? bhh_b : bhh_f;
  float bs[4];
  #pragma unroll
  for (int g = 0; g < 4; g++) bs[g] = bih[g*256 + hcol] + bhh[g*256 + hcol];
  float wo = Wout[dir*256 + hcol];
  float creg[16];
  #pragma unroll
  for (int r = 0; r < 16; r++) creg[r] = 0.0f;
  const int wbase = (hcol >> 4)*512 + ((hcol >> 3) & 1)*256 + (hcol & 7);
  const size_t m3base = (size_t)0;
  __syncthreads();

#define L2_ISSUEA(c, slot, areg) do{ \
    areg = *(const f16x8*)(arow2 + (c)*16); \
    const _Float16* gp_ = wsw2 + (size_t)(c)*2048; \
    _Float16* lp_ = ringw + (slot)*2048; \
    gll16(gp_,        lp_); \
    gll16(gp_ +  512, lp_ +  512); \
    gll16(gp_ + 1024, lp_ + 1024); \
    gll16(gp_ + 1536, lp_ + 1536); }while(0)
#define L2_ISSUEB(c, slot) do{ \
    const _Float16* gp_ = wsw2 + (size_t)(c)*2048; \
    _Float16* lp_ = ringw + (slot)*2048; \
    gll16(gp_,        lp_); \
    gll16(gp_ +  512, lp_ +  512); \
    gll16(gp_ + 1024, lp_ + 1024); \
    gll16(gp_ + 1536, lp_ + 1536); }while(0)
#define L2_MFMA4(a_, slot) do{ \
    const _Float16* rb_ = ringw + (slot)*2048 + lane*8; \
    f16x8 b0_ = *(const f16x8*)(rb_); \
    f16x8 b1_ = *(const f16x8*)(rb_ +  512); \
    f16x8 b2_ = *(const f16x8*)(rb_ + 1024); \
    f16x8 b3_ = *(const f16x8*)(rb_ + 1536); \
    acc[0] = __builtin_amdgcn_mfma_f32_32x32x16_f16(a_, b0_, acc[0], 0,0,0); \
    acc[1] = __builtin_amdgcn_mfma_f32_32x32x16_f16(a_, b1_, acc[1], 0,0,0); \
    acc[2] = __builtin_amdgcn_mfma_f32_32x32x16_f16(a_, b2_, acc[2], 0,0,0); \
    acc[3] = __builtin_amdgcn_mfma_f32_32x32x16_f16(a_, b3_, acc[3], 0,0,0); }while(0)
#define L2_CONSUME_P2(c, slot) do{ \
    f16x8 a_ = *(const f16x8*)(smem + ((c)-32)*512 + lane*8); \
    L2_MFMA4(a_, slot); }while(0)

  for (int s = 0; s < T_; s++){
    const int tin = dir ? (T_-1-s) : s;
    const _Float16* arow2 = p1m + ((size_t)tin*B_ + b0 + (lane & 31))*512 + ((lane >> 5) << 3);

    f32x16 acc[4];
    #pragma unroll
    for (int g = 0; g < 4; g++)
      #pragma unroll
      for (int e = 0; e < 16; e++) acc[g][e] = 0.0f;

    f16x8 aE, aO;
    L2_ISSUEA(0, 0, aE); L2_ISSUEA(1, 1, aO);
    // phase 1: input GEMM, batches are 5 vmem ops (A-load + 4 DMA)
    for (int c = 0; c < 30; c += 2){
      WAITV(5); L2_MFMA4(aE, 0); WAITL0; L2_ISSUEA(c+2, 0, aE);
      WAITV(5); L2_MFMA4(aO, 1); WAITL0; L2_ISSUEA(c+3, 1, aO);
    }
    WAITV(5); L2_MFMA4(aE, 0); WAITL0; L2_ISSUEB(32, 0);   // c=30
    WAITV(4); L2_MFMA4(aO, 1); WAITL0; L2_ISSUEB(33, 1);   // c=31
    // phase 2: recurrent GEMM, batches are 4 vmem ops
    for (int c = 32; c < 46; c += 2){
      WAITV(4); L2_CONSUME_P2(c,   0); WAITL0; L2_ISSUEB(c+2, 0);
      WAITV(4); L2_CONSUME_P2(c+1, 1); WAITL0; L2_ISSUEB(c+3, 1);
    }
    WAITV(4); L2_CONSUME_P2(46, 0);
    WAITV(0); L2_CONSUME_P2(47, 1);

    __syncthreads();     // smem-h reads done before overwrite

    #pragma unroll
    for (int r = 0; r < 16; r++){
      const int row = (r & 3) + 8*(r >> 2) + hi4;
      const int b = b0 + row;
      float m3 = mask3[(size_t)b*H_ + hcol + m3base];
      float m4 = mask4[(size_t)b*512 + dir*256 + hcol] * wo;
      float gi = acc[0][r] + bs[0];
      float gf = acc[1][r] + bs[1];
      float gg = acc[2][r] + bs[2];
      float go = acc[3][r] + bs[3];
      float ii = sigm(gi), ff = sigm(gf), g2 = tanh_(gg), oo = sigm(go);
      float cn = ff*creg[r] + ii*g2;
      creg[r] = cn;
      float h = oo*tanh_(cn);
      smem[wbase + row*8] = (_Float16)(h * m3);
      float contrib = h * m4;
      contrib += __shfl_xor(contrib, 16);
      contrib += __shfl_xor(contrib, 8);
      contrib += __shfl_xor(contrib, 4);
      contrib += __shfl_xor(contrib, 2);
      contrib += __shfl_xor(contrib, 1);
      if ((lane & 31) == 0) atomicAdd(&pred[(size_t)b*T_ + s], contrib);
    }
    __syncthreads();
  }
#undef L2_ISSUEA
#undef L2_ISSUEB
#undef L2_MFMA4
#undef L2_CONSUME_P2
}

__global__ void prep_kernel(const float* __restrict__ x0, float* __restrict__ mvec)
{
  int b = blockIdx.x*blockDim.x + threadIdx.x;
  if (b < B_){
    float ssum = 0.0f;
    for (int t = 0; t < T_; t++) ssum += x0[b*T_ + t];
    mvec[b] = ssum * (1.0f / T_);
  }
}

// xT[t*B + b] = x0[b*T + t]
__global__ void prep2_kernel(const float* __restrict__ x0, float* __restrict__ xT)
{
  int idx = blockIdx.x*256 + threadIdx.x;
  if (idx < B_*T_){
    int t = idx >> 10;
    int b = idx & 1023;
    xT[idx] = x0[b*T_ + t];
  }
}

__global__ void final_kernel(const float* __restrict__ pred,
                             const float* __restrict__ mvec,
                             const float* __restrict__ bout,
                             float* __restrict__ out)
{
  int idx = blockIdx.x*256 + threadIdx.x;
  if (idx < B_*T_){
    int b = idx / T_;
    out[idx] = pred[idx] + bout[0] + mvec[b];
  }
}

extern "C" void kernel_launch(void* const* d_in, const int* in_sizes, int n_in,
                              void* d_out, int out_size, void* d_ws, size_t ws_size,
                              hipStream_t stream)
{
  (void)in_sizes; (void)n_in; (void)out_size; (void)ws_size;
  const float* x0    = (const float*)d_in[0];
  const float* Wih1f = (const float*)d_in[1];
  const float* Whh1f = (const float*)d_in[2];
  const float* bih1f = (const float*)d_in[3];
  const float* bhh1f = (const float*)d_in[4];
  const float* Wih1b = (const float*)d_in[5];
  const float* Whh1b = (const float*)d_in[6];
  const float* bih1b = (const float*)d_in[7];
  const float* bhh1b = (const float*)d_in[8];
  const float* Wih2f = (const float*)d_in[9];
  const float* Whh2f = (const float*)d_in[10];
  const float* bih2f = (const float*)d_in[11];
  const float* bhh2f = (const float*)d_in[12];
  const float* Wih2b = (const float*)d_in[13];
  const float* Whh2b = (const float*)d_in[14];
  const float* bih2b = (const float*)d_in[15];
  const float* bhh2b = (const float*)d_in[16];
  const float* Wout  = (const float*)d_in[17];
  const float* bout  = (const float*)d_in[18];
  const float* mask1 = (const float*)d_in[19];
  const float* mask2 = (const float*)d_in[20];
  const float* mask3 = (const float*)d_in[21];
  const float* mask4 = (const float*)d_in[22];
  float* out = (float*)d_out;

  // Workspace layout (~110 MB)
  char* ws = (char*)d_ws;
  size_t off = 0;
  _Float16* wpool = (_Float16*)(ws + off); off += (size_t)W_TOTAL*2;        // 4.2 MB
  _Float16* p1m   = (_Float16*)(ws + off); off += (size_t)T_*B_*512*2;      // 104.8 MB
  float* pred = (float*)(ws + off); off += (size_t)B_*T_*4;                 // 0.4 MB
  float* xT   = (float*)(ws + off); off += (size_t)B_*T_*4;                 // 0.4 MB
  float* mvec = (float*)(ws + off); off += 4096;

  hipMemsetAsync(pred, 0, (size_t)B_*T_*4, stream);

  pack_weights<<<dim3(1024), dim3(256), 0, stream>>>(
      Whh1f, Whh1b, Wih2f, Wih2b, Whh2f, Whh2b, wpool);
  prep_kernel<<<dim3(4), dim3(256), 0, stream>>>(x0, mvec);
  prep2_kernel<<<dim3((B_*T_ + 255)/256), dim3(256), 0, stream>>>(x0, xT);

  l1_phase<<<dim3(64), dim3(512), 0, stream>>>(wpool, Wih1f, Wih1b,
      bih1f, bhh1f, bih1b, bhh1b, xT, mvec, mask1, mask2, p1m);
  l2_phase<<<dim3(64), dim3(512), 0, stream>>>(wpool, bih2f, bhh2f,
      bih2b, bhh2b, p1m, mask3, mask4, Wout, pred);
  final_kernel<<<dim3((B_*T_ + 255)/256), dim3(256), 0, stream>>>(pred, mvec, bout, out);
}